// Round 11
// baseline (571.682 us; speedup 1.0000x reference)
//
#include <hip/hip_runtime.h>
#include <cstdint>

// ---------------------------------------------------------------------------
// GCNRecommender round 14:
//  - R13 post-mortem: profile is flat (13 kernels all <58us); l45 v2 neutral
//    vs R9. Next lever: remove whole passes. Layer 2 fused into ONE kernel:
//      l2_kernel = gather-agg(h1) -> LDS As -> reg-B GEMM(K=128,N=256)
//                  -> LN(256)+ELU -> bf16 out.
//    Kills agg_kernel + mfma_gemm(L2) + ln_elu: 2 roundtrips (12.8+25.6MB
//    w+r) and 2 launches. 512-thr blocks, 8 waves x 16 rows, acc[16],
//    B frags from L2-resident W2t (no Bs staging, 1 barrier total).
//  - everything else unchanged from round 13 (verified, 497.1us).
// ---------------------------------------------------------------------------

#define LN_EPS 1e-5f

typedef __attribute__((ext_vector_type(8))) short bf16x8;
typedef __attribute__((ext_vector_type(4))) float f32x4;

static __device__ __forceinline__ ushort f2bf(float f) {
  union { float f; uint u; } c; c.f = f;
  uint u = c.u;
  return (ushort)((u + 0x7fffu + ((u >> 16) & 1u)) >> 16);  // RNE
}
static __device__ __forceinline__ float bf2f(ushort h) {
  union { uint u; float f; } c; c.u = (uint)h << 16;
  return c.f;
}

// ---------------- CSR build ----------------

__global__ void deg_kernel(const int* __restrict__ dst, int* __restrict__ deg, int E) {
  int e = blockIdx.x * blockDim.x + threadIdx.x;
  if (e < E) atomicAdd(&deg[dst[e]], 1);
}

__global__ void scan1_kernel(const int* __restrict__ deg, int* __restrict__ excl,
                             int* __restrict__ bsums, float* __restrict__ dinv, int N) {
  __shared__ int s[256];
  int tid = threadIdx.x;
  int i = blockIdx.x * 256 + tid;
  int v = (i < N) ? deg[i] : 0;
  s[tid] = v;
  __syncthreads();
  for (int o = 1; o < 256; o <<= 1) {
    int t = (tid >= o) ? s[tid - o] : 0;
    __syncthreads();
    if (tid >= o) s[tid] += t;
    __syncthreads();
  }
  if (i < N) {
    excl[i] = s[tid] - v;
    dinv[i] = rsqrtf((float)v + 1.0f);  // +1 self-loop
  }
  if (tid == 255) bsums[blockIdx.x] = s[tid];
}

// finalize rowptr (+ block-sum offset computed in-kernel) and seed fill cursor
__global__ void scan23_kernel(int* __restrict__ rowptr, int* __restrict__ fill,
                              const int* __restrict__ bsums, int N, int Etotal, int nb) {
  __shared__ int sh[256];
  const int tid = threadIdx.x;
  const int bix = blockIdx.x;
  int v = (tid < bix && tid < nb) ? bsums[tid] : 0;
  sh[tid] = v;
  __syncthreads();
  for (int o = 128; o > 0; o >>= 1) {
    if (tid < o) sh[tid] += sh[tid + o];
    __syncthreads();
  }
  const int off = sh[0];
  int i = bix * 256 + tid;
  if (i < N) {
    int r = rowptr[i] + off;
    rowptr[i] = r;
    fill[i] = r;
  } else if (i == N) {
    rowptr[N] = Etotal;
  }
}

__global__ void fill_kernel(const int* __restrict__ src, const int* __restrict__ dst,
                            int* __restrict__ fill, int* __restrict__ srcs, int E) {
  int e = blockIdx.x * blockDim.x + threadIdx.x;
  if (e >= E) return;
  int idx = atomicAdd(&fill[dst[e]], 1);
  srcs[idx] = src[e];
}

// ---------------- prep: weight convert + deg zero + Wl2t pad ----------------

struct WConvArgs {
  const float* w[5];
  ushort* wt[5];
  int K[5], N[5];
  int off[6];
};

__global__ void prep_kernel(WConvArgs a, int total, int* __restrict__ deg, int Nn) {
  int i = blockIdx.x * blockDim.x + threadIdx.x;
  if (i < Nn) deg[i] = 0;
  if (i < 768) a.wt[4][32000 + i] = 0;  // zero pad rows 500..511 of Wl2t
  if (i >= total) return;
  int m = 0;
  while (i >= a.off[m + 1]) m++;
  int j = i - a.off[m];
  int k = j / a.N[m], n = j - k * a.N[m];
  a.wt[m][(size_t)n * a.K[m] + k] = f2bf(a.w[m][j]);
}

// ---------------- bf16 MFMA GEMM ----------------
// C[M][N] = A[M][K] @ Bt[N][K]^T (+ bias). K % 32 == 0.
// AF32: A is fp32, converted to bf16 during LDS staging. Output bf16.
#define TBM 128
#define TBN 128
#define TBK 32
#define LDK 40

template <int AF32>
__global__ __launch_bounds__(256, 2) void mfma_gemm_kernel(
    const void* __restrict__ A, const ushort* __restrict__ Bt,
    const float* __restrict__ bias, ushort* __restrict__ Cout,
    int M, int N, int K) {
  __shared__ ushort As[TBM][LDK];
  __shared__ ushort Bs[TBN][LDK];
  const int tid = threadIdx.x;
  const int lane = tid & 63;
  const int w = tid >> 6;
  const int wm = w & 1, wn = w >> 1;
  const int quad = lane >> 4, l16 = lane & 15;
  const int rowBase = blockIdx.y * TBM;
  const int colBase = blockIdx.x * TBN;

  f32x4 acc[4][4] = {};
  const int lr = tid >> 2;
  const int lk = (tid & 3) * 8;

  for (int k0 = 0; k0 < K; k0 += TBK) {
#pragma unroll
    for (int h = 0; h < 2; h++) {
      int r = lr + h * 64;
      int grow = rowBase + r;
      if (AF32) {
        const float* Af = (const float*)A;
        float4 v0 = make_float4(0.f, 0.f, 0.f, 0.f), v1 = v0;
        if (grow < M) {
          const float* ap = Af + (size_t)grow * K + k0 + lk;
          v0 = *(const float4*)ap;
          v1 = *(const float4*)(ap + 4);
        }
        uint4 wv;
        wv.x = (uint)f2bf(v0.x) | ((uint)f2bf(v0.y) << 16);
        wv.y = (uint)f2bf(v0.z) | ((uint)f2bf(v0.w) << 16);
        wv.z = (uint)f2bf(v1.x) | ((uint)f2bf(v1.y) << 16);
        wv.w = (uint)f2bf(v1.z) | ((uint)f2bf(v1.w) << 16);
        *(uint4*)&As[r][lk] = wv;
      } else {
        const ushort* Ab = (const ushort*)A;
        uint4 va = make_uint4(0, 0, 0, 0);
        if (grow < M) va = *(const uint4*)(Ab + (size_t)grow * K + k0 + lk);
        *(uint4*)&As[r][lk] = va;
      }
      int gcol = colBase + r;
      uint4 vb = make_uint4(0, 0, 0, 0);
      if (gcol < N) vb = *(const uint4*)(Bt + (size_t)gcol * K + k0 + lk);
      *(uint4*)&Bs[r][lk] = vb;
    }
    __syncthreads();
    bf16x8 af[4], bfr[4];
#pragma unroll
    for (int i = 0; i < 4; i++) {
      af[i]  = *(const bf16x8*)&As[wm * 64 + i * 16 + l16][quad * 8];
      bfr[i] = *(const bf16x8*)&Bs[wn * 64 + i * 16 + l16][quad * 8];
    }
#pragma unroll
    for (int i = 0; i < 4; i++)
#pragma unroll
      for (int j = 0; j < 4; j++)
        acc[i][j] = __builtin_amdgcn_mfma_f32_16x16x32_bf16(af[i], bfr[j], acc[i][j], 0, 0, 0);
    __syncthreads();
  }
#pragma unroll
  for (int i = 0; i < 4; i++) {
    int row0 = rowBase + wm * 64 + i * 16 + quad * 4;
#pragma unroll
    for (int j = 0; j < 4; j++) {
      int col = colBase + wn * 64 + j * 16 + l16;
      if (col >= N) continue;
      float bv = bias ? bias[col] : 0.f;
#pragma unroll
      for (int r = 0; r < 4; r++) {
        int row = row0 + r;
        if (row >= M) continue;
        Cout[(size_t)row * N + col] = f2bf(acc[i][j][r] + bv);
      }
    }
  }
}

// ---------------- aggregation helper ----------------

static __device__ __forceinline__ void acc8(float* a, uint4 v, float c) {
  a[0] += c * bf2f((ushort)(v.x & 0xffffu)); a[1] += c * bf2f((ushort)(v.x >> 16));
  a[2] += c * bf2f((ushort)(v.y & 0xffffu)); a[3] += c * bf2f((ushort)(v.y >> 16));
  a[4] += c * bf2f((ushort)(v.z & 0xffffu)); a[5] += c * bf2f((ushort)(v.z >> 16));
  a[6] += c * bf2f((ushort)(v.w & 0xffffu)); a[7] += c * bf2f((ushort)(v.w >> 16));
}

// ---------------- fused layer 2 ----------------
// h2 = elu(LN256(Agg(h1) @ W2 + b2)); Agg(h1@W2) == Agg(h1)@W2 (linearity).
// Per 128-row block (512 thr, 8 waves):
//   phase A: gather-aggregate 128 nodes into As[128][136] bf16 (waves
//            interleaved over rows; verified agg inner loop; 1 barrier).
//   phase B: wave w owns rows w*16..w*16+15, all 256 cols: acc[16] f32x4,
//            B frags straight from L2-resident W2t (64KB), no Bs staging.
//   phase C: LN(256) per row in-wave (16 in-reg cols x 16-lane shfl) + ELU,
//            bf16 store.
// LDS 34816B; ~2 blocks/CU.
__global__ __launch_bounds__(512) void l2_kernel(
    const ushort* __restrict__ Hin, const int* __restrict__ rowptr,
    const int* __restrict__ srcs, const float* __restrict__ dinv,
    const ushort* __restrict__ W2t, const float* __restrict__ bias,
    const float* __restrict__ gamma, const float* __restrict__ beta,
    ushort* __restrict__ Hout, int M) {
  __shared__ ushort As[128][136];
  const int tid = threadIdx.x;
  const int lane = tid & 63;
  const int w = tid >> 6;                 // 0..7
  const int g = lane >> 4, l16 = lane & 15;
  const int rowBase = blockIdx.x * 128;

  // ---- phase A: gather-aggregate ----
  const uint4* h4 = (const uint4*)Hin;
  for (int it = 0; it < 16; ++it) {
    const int lrow = it * 8 + w;          // 0..127, interleaved over waves
    const int n = rowBase + lrow;
    if (n < M) {
      const float di = dinv[n];
      float a[8] = {0.f, 0.f, 0.f, 0.f, 0.f, 0.f, 0.f, 0.f};
      if (g == 0) {
        uint4 sv = h4[(size_t)n * 16 + l16];
        acc8(a, sv, di * di);
      }
      int i = rowptr[n] + g;
      const int e = rowptr[n + 1];
      for (; i + 4 < e; i += 8) {
        int s0 = srcs[i], s1 = srcs[i + 4];
        float c0 = dinv[s0] * di, c1 = dinv[s1] * di;
        uint4 v0 = h4[(size_t)s0 * 16 + l16];
        uint4 v1 = h4[(size_t)s1 * 16 + l16];
        acc8(a, v0, c0);
        acc8(a, v1, c1);
      }
      if (i < e) {
        int s = srcs[i];
        float c = dinv[s] * di;
        uint4 v = h4[(size_t)s * 16 + l16];
        acc8(a, v, c);
      }
#pragma unroll
      for (int k = 0; k < 8; k++) {
        a[k] += __shfl_xor(a[k], 16);
        a[k] += __shfl_xor(a[k], 32);
      }
      if (g == 0) {
        uint4 o;
        o.x = (uint)f2bf(a[0]) | ((uint)f2bf(a[1]) << 16);
        o.y = (uint)f2bf(a[2]) | ((uint)f2bf(a[3]) << 16);
        o.z = (uint)f2bf(a[4]) | ((uint)f2bf(a[5]) << 16);
        o.w = (uint)f2bf(a[6]) | ((uint)f2bf(a[7]) << 16);
        *(uint4*)&As[lrow][l16 * 8] = o;
      }
    }
  }
  __syncthreads();

  // ---- phase B: GEMM rows w*16..w*16+15 x 256 cols, K=128 ----
  const int quad = g;
  const int wrow = w * 16;
  f32x4 acc[16] = {};
#pragma unroll
  for (int k0 = 0; k0 < 128; k0 += 32) {
    bf16x8 af = *(const bf16x8*)&As[wrow + l16][k0 + quad * 8];
#pragma unroll
    for (int j = 0; j < 16; j++) {
      bf16x8 bf = *(const bf16x8*)(W2t + (size_t)(j * 16 + l16) * 128 + k0 + quad * 8);
      acc[j] = __builtin_amdgcn_mfma_f32_16x16x32_bf16(af, bf, acc[j], 0, 0, 0);
    }
  }

  // ---- phase C: bias + LN(256) + ELU -> bf16 ----
#pragma unroll
  for (int r = 0; r < 4; r++) {
    float v[16];
    float s = 0.f;
#pragma unroll
    for (int j = 0; j < 16; j++) {
      v[j] = acc[j][r] + bias[j * 16 + l16];
      s += v[j];
    }
#pragma unroll
    for (int o = 8; o >= 1; o >>= 1) s += __shfl_xor(s, o, 16);
    float mean = s * (1.0f / 256.0f);
    float q = 0.f;
#pragma unroll
    for (int j = 0; j < 16; j++) {
      float d = v[j] - mean;
      q += d * d;
    }
#pragma unroll
    for (int o = 8; o >= 1; o >>= 1) q += __shfl_xor(q, o, 16);
    float rstd = rsqrtf(q * (1.0f / 256.0f) + LN_EPS);
    int grow = rowBase + wrow + quad * 4 + r;
    if (grow < M) {
#pragma unroll
      for (int j = 0; j < 16; j++) {
        int col = j * 16 + l16;
        float y = (v[j] - mean) * rstd * gamma[col] + beta[col];
        y = (y > 0.f) ? y : expm1f(y);
        Hout[(size_t)grow * 256 + col] = f2bf(y);
      }
    }
  }
}

// ---------------- fused L4+L5 (v2, verified R13) ----------------
__global__ __launch_bounds__(256) void l45_kernel(
    const ushort* __restrict__ A, const ushort* __restrict__ Bt1,
    const float* __restrict__ bias1, const float* __restrict__ gamma,
    const float* __restrict__ beta, const ushort* __restrict__ Bt2,
    const float* __restrict__ bias2, float* __restrict__ Cout, int M) {
  __shared__ ushort h4s[64][68];
  __shared__ __align__(16) float sout[16][500];
  const int tid = threadIdx.x;
  const int lane = tid & 63;
  const int w = tid >> 6;
  const int quad = lane >> 4, l16 = lane & 15;
  const int rowBase = blockIdx.x * 64;        // block's 64 rows
  const int waveRow = rowBase + w * 16;       // this wave's 16 rows

  // ---- phase 1: reg-B GEMM(K=128,N=64) + bias + LN + ELU -> h4s ----
  bf16x8 bfr1[4][4];
#pragma unroll
  for (int j = 0; j < 4; j++)
#pragma unroll
    for (int kk = 0; kk < 4; kk++)
      bfr1[j][kk] = *(const bf16x8*)(Bt1 + (size_t)(j * 16 + l16) * 128 + kk * 32 + quad * 8);

  const int arow = waveRow + l16;
  bf16x8 af[4] = {};
  if (arow < M) {
#pragma unroll
    for (int kk = 0; kk < 4; kk++)
      af[kk] = *(const bf16x8*)(A + (size_t)arow * 128 + kk * 32 + quad * 8);
  }

  f32x4 acc1[4] = {};
#pragma unroll
  for (int j = 0; j < 4; j++)
#pragma unroll
    for (int kk = 0; kk < 4; kk++)
      acc1[j] = __builtin_amdgcn_mfma_f32_16x16x32_bf16(af[kk], bfr1[j][kk], acc1[j], 0, 0, 0);

#pragma unroll
  for (int r = 0; r < 4; r++) {
    float v[4];
    float s = 0.f;
#pragma unroll
    for (int j = 0; j < 4; j++) {
      v[j] = acc1[j][r] + bias1[j * 16 + l16];
      s += v[j];
    }
#pragma unroll
    for (int o = 8; o >= 1; o >>= 1) s += __shfl_xor(s, o, 16);
    float mean = s * (1.0f / 64.0f);
    float q = 0.f;
#pragma unroll
    for (int j = 0; j < 4; j++) {
      float d = v[j] - mean;
      q += d * d;
    }
#pragma unroll
    for (int o = 8; o >= 1; o >>= 1) q += __shfl_xor(q, o, 16);
    float rstd = rsqrtf(q * (1.0f / 64.0f) + LN_EPS);
    int lrow = w * 16 + quad * 4 + r;  // local row 0..63
#pragma unroll
    for (int j = 0; j < 4; j++) {
      int col = j * 16 + l16;
      float y = (v[j] - mean) * rstd * gamma[col] + beta[col];
      y = (y > 0.f) ? y : expm1f(y);
      h4s[lrow][col] = f2bf(y);
    }
  }

  // preload phase-2 B fragments + bias (overlaps with other waves' phase 1)
  bf16x8 breg[8][2];
  float bvreg[8];
#pragma unroll
  for (int c = 0; c < 8; c++) {
    const int bcol = (w * 8 + c) * 16 + l16;  // 0..511
    breg[c][0] = *(const bf16x8*)(Bt2 + (size_t)bcol * 64 + quad * 8);
    breg[c][1] = *(const bf16x8*)(Bt2 + (size_t)bcol * 64 + 32 + quad * 8);
    bvreg[c] = (bcol < 500) ? bias2[bcol] : 0.f;
  }
  __syncthreads();

  // ---- phase 2: 4 slabs of 16 rows ----
#pragma unroll 1
  for (int rt = 0; rt < 4; rt++) {
    bf16x8 a0 = *(const bf16x8*)&h4s[rt * 16 + l16][quad * 8];
    bf16x8 a1 = *(const bf16x8*)&h4s[rt * 16 + l16][quad * 8 + 32];
#pragma unroll
    for (int c = 0; c < 8; c++) {
      f32x4 pacc = {0.f, 0.f, 0.f, 0.f};
      pacc = __builtin_amdgcn_mfma_f32_16x16x32_bf16(a0, breg[c][0], pacc, 0, 0, 0);
      pacc = __builtin_amdgcn_mfma_f32_16x16x32_bf16(a1, breg[c][1], pacc, 0, 0, 0);
      const int col = (w * 8 + c) * 16 + l16;
      if (col < 500) {
#pragma unroll
        for (int r = 0; r < 4; r++)
          sout[quad * 4 + r][col] = pacc[r] + bvreg[c];
      }
    }
    __syncthreads();
    // write 16 rows x 500 floats as contiguous float4 runs
#pragma unroll
    for (int k = 0; k < 8; k++) {
      int idx = k * 256 + tid;  // 0..2047; 2000 valid (16 rows * 125 float4)
      if (idx < 2000) {
        int r = idx / 125;
        int c4 = idx - r * 125;
        int grow = rowBase + rt * 16 + r;
        if (grow < M) {
          float4 v = *(float4*)&sout[r][c4 * 4];
          *(float4*)&Cout[(size_t)grow * 500 + c4 * 4] = v;
        }
      }
    }
    __syncthreads();
  }
}

// ---------------- agg + bias + LN(128) + ELU (layers 1 and 3) ----------------
__global__ __launch_bounds__(256) void agg_ln_kernel(
    const ushort* __restrict__ hb, const int* __restrict__ rowptr,
    const int* __restrict__ srcs, const float* __restrict__ dinv,
    const float* __restrict__ bias, const float* __restrict__ gamma,
    const float* __restrict__ beta, uint* __restrict__ out, int Nn) {
  const int wave = threadIdx.x >> 6;
  const int n = blockIdx.x * 4 + wave;
  if (n >= Nn) return;
  const int lane = threadIdx.x & 63;
  const int g = lane >> 4, l16 = lane & 15;
  const uint4* h4 = (const uint4*)hb;
  const float di = dinv[n];
  float a[8] = {0.f, 0.f, 0.f, 0.f, 0.f, 0.f, 0.f, 0.f};
  if (g == 0) {
    uint4 sv = h4[(size_t)n * 16 + l16];
    acc8(a, sv, di * di);
    float4 b0 = ((const float4*)bias)[l16 * 2];
    float4 b1 = ((const float4*)bias)[l16 * 2 + 1];
    a[0] += b0.x; a[1] += b0.y; a[2] += b0.z; a[3] += b0.w;
    a[4] += b1.x; a[5] += b1.y; a[6] += b1.z; a[7] += b1.w;
  }
  int i = rowptr[n] + g;
  const int e = rowptr[n + 1];
  for (; i + 4 < e; i += 8) {
    int s0 = srcs[i], s1 = srcs[i + 4];
    float c0 = dinv[s0] * di, c1 = dinv[s1] * di;
    uint4 v0 = h4[(size_t)s0 * 16 + l16];
    uint4 v1 = h4[(size_t)s1 * 16 + l16];
    acc8(a, v0, c0);
    acc8(a, v1, c1);
  }
  if (i < e) {
    int s = srcs[i];
    float c = dinv[s] * di;
    uint4 v = h4[(size_t)s * 16 + l16];
    acc8(a, v, c);
  }
#pragma unroll
  for (int k = 0; k < 8; k++) {
    a[k] += __shfl_xor(a[k], 16);
    a[k] += __shfl_xor(a[k], 32);
  }
  float s = ((a[0] + a[1]) + (a[2] + a[3])) + ((a[4] + a[5]) + (a[6] + a[7]));
  s += __shfl_xor(s, 8);
  s += __shfl_xor(s, 4);
  s += __shfl_xor(s, 2);
  s += __shfl_xor(s, 1);
  float mean = s * (1.0f / 128.0f);
  float q = 0.f;
#pragma unroll
  for (int k = 0; k < 8; k++) {
    float d = a[k] - mean;
    q += d * d;
  }
  q += __shfl_xor(q, 8);
  q += __shfl_xor(q, 4);
  q += __shfl_xor(q, 2);
  q += __shfl_xor(q, 1);
  float rstd = rsqrtf(q * (1.0f / 128.0f) + LN_EPS);
  if (g == 0) {
    float4 g0 = ((const float4*)gamma)[l16 * 2];
    float4 g1 = ((const float4*)gamma)[l16 * 2 + 1];
    float4 e0 = ((const float4*)beta)[l16 * 2];
    float4 e1 = ((const float4*)beta)[l16 * 2 + 1];
    float gv[8] = {g0.x, g0.y, g0.z, g0.w, g1.x, g1.y, g1.z, g1.w};
    float ev[8] = {e0.x, e0.y, e0.z, e0.w, e1.x, e1.y, e1.z, e1.w};
    float y[8];
#pragma unroll
    for (int k = 0; k < 8; k++) {
      float t = (a[k] - mean) * rstd * gv[k] + ev[k];
      y[k] = (t > 0.f) ? t : expm1f(t);
    }
    uint4 o;
    o.x = (uint)f2bf(y[0]) | ((uint)f2bf(y[1]) << 16);
    o.y = (uint)f2bf(y[2]) | ((uint)f2bf(y[3]) << 16);
    o.z = (uint)f2bf(y[4]) | ((uint)f2bf(y[5]) << 16);
    o.w = (uint)f2bf(y[6]) | ((uint)f2bf(y[7]) << 16);
    ((uint4*)out)[(size_t)n * 16 + l16] = o;
  }
}

// ---------------- host ----------------

extern "C" void kernel_launch(void* const* d_in, const int* in_sizes, int n_in,
                              void* d_out, int out_size, void* d_ws, size_t ws_size,
                              hipStream_t stream) {
  const float* x   = (const float*)d_in[0];
  const int*   ei  = (const int*)d_in[1];
  const float* W1  = (const float*)d_in[2];
  const float* b1  = (const float*)d_in[3];
  const float* g1  = (const float*)d_in[4];
  const float* be1 = (const float*)d_in[5];
  const float* W2  = (const float*)d_in[6];
  const float* b2  = (const float*)d_in[7];
  const float* g2  = (const float*)d_in[8];
  const float* be2 = (const float*)d_in[9];
  const float* W3  = (const float*)d_in[10];
  const float* b3  = (const float*)d_in[11];
  const float* g3  = (const float*)d_in[12];
  const float* be3 = (const float*)d_in[13];
  const float* Wl1 = (const float*)d_in[14];
  const float* bl1 = (const float*)d_in[15];
  const float* g4  = (const float*)d_in[16];
  const float* be4 = (const float*)d_in[17];
  const float* Wl2 = (const float*)d_in[18];
  const float* bl2 = (const float*)d_in[19];

  const int N = in_sizes[0] / 128;  // 50000
  const int E = in_sizes[1] / 2;    // 800000
  const int* esrc = ei;
  const int* edst = ei + E;

  // workspace layout
  char* p = (char*)d_ws;
  ushort* Pb = (ushort*)p;            p += (size_t)N * 256 * 2;  // bf16 act buf
  ushort* Qb = (ushort*)p;            p += (size_t)N * 256 * 2;
  ushort* W1t = (ushort*)p;           p += 128 * 128 * 2;
  ushort* W2t = (ushort*)p;           p += 128 * 256 * 2;
  ushort* W3t = (ushort*)p;           p += 256 * 128 * 2;
  ushort* Wl1t = (ushort*)p;          p += 128 * 64 * 2;
  ushort* Wl2t = (ushort*)p;          p += 64 * 512 * 2;  // padded to 512 rows
  int*   srcs  = (int*)p;             p += (size_t)E * 4;
  int*   deg   = (int*)p;             p += (size_t)N * 4;
  float* dinv  = (float*)p;           p += (size_t)N * 4;
  int*   rowptr= (int*)p;             p += (size_t)(N + 2) * 4;
  int*   fill  = (int*)p;             p += (size_t)N * 4;
  int*   bsums = (int*)p;             p += 256 * 4;

  const int nb = (N + 255) / 256;
  const int eb = (E + 255) / 256;

  // ---- prep: weight convert + deg zero + Wl2t pad (one launch) ----
  WConvArgs wa;
  wa.w[0] = W1;  wa.wt[0] = W1t;  wa.K[0] = 128; wa.N[0] = 128;
  wa.w[1] = W2;  wa.wt[1] = W2t;  wa.K[1] = 128; wa.N[1] = 256;
  wa.w[2] = W3;  wa.wt[2] = W3t;  wa.K[2] = 256; wa.N[2] = 128;
  wa.w[3] = Wl1; wa.wt[3] = Wl1t; wa.K[3] = 128; wa.N[3] = 64;
  wa.w[4] = Wl2; wa.wt[4] = Wl2t; wa.K[4] = 64;  wa.N[4] = 500;
  wa.off[0] = 0;
  for (int m = 0; m < 5; m++) wa.off[m + 1] = wa.off[m] + wa.K[m] * wa.N[m];
  int wtotal = wa.off[5];
  int ptotal = wtotal > N ? wtotal : N;
  prep_kernel<<<(ptotal + 255) / 256, 256, 0, stream>>>(wa, wtotal, deg, N);

  // ---- CSR build ----
  deg_kernel<<<eb, 256, 0, stream>>>(edst, deg, E);
  scan1_kernel<<<nb, 256, 0, stream>>>(deg, rowptr, bsums, dinv, N);
  scan23_kernel<<<(N + 256) / 256, 256, 0, stream>>>(rowptr, fill, bsums, N, E, nb);
  fill_kernel<<<eb, 256, 0, stream>>>(esrc, edst, fill, srcs, E);

  const int ab = (N + 3) / 4;
  auto grid_of = [&](int M, int Nn) {
    return dim3((Nn + TBN - 1) / TBN, (M + TBM - 1) / TBM);
  };

  // L1: h1 = elu(LN(Agg(x@W1) + b1))   -- x converted fp32->bf16 in-GEMM
  mfma_gemm_kernel<1><<<grid_of(N, 128), 256, 0, stream>>>(
      x, W1t, nullptr, Pb, N, 128, 128);
  agg_ln_kernel<<<ab, 256, 0, stream>>>(Pb, rowptr, srcs, dinv, b1, g1, be1, (uint*)Qb, N);

  // L2 (fused): h2 = elu(LN(Agg(h1)@W2 + b2))
  l2_kernel<<<dim3((N + 127) / 128), 512, 0, stream>>>(
      Qb, rowptr, srcs, dinv, W2t, b2, g2, be2, Pb, N);

  // L3: h3 = elu(LN(Agg(h2@W3) + b3))
  mfma_gemm_kernel<0><<<grid_of(N, 128), 256, 0, stream>>>(
      Pb, W3t, nullptr, Qb, N, 128, 256);
  agg_ln_kernel<<<ab, 256, 0, stream>>>(Qb, rowptr, srcs, dinv, b3, g3, be3, (uint*)Pb, N);

  // L4+L5 fused v2: out = elu(LN(h3@Wl1 + bl1)) @ Wl2 + bl2
  l45_kernel<<<dim3((N + 63) / 64), 256, 0, stream>>>(
      Pb, Wl1t, bl1, g4, be4, Wl2t, bl2, (float*)d_out, N);
}

// Round 13
// 482.501 us; speedup vs baseline: 1.1848x; 1.1848x over previous
//
#include <hip/hip_runtime.h>
#include <cstdint>

// ---------------------------------------------------------------------------
// GCNRecommender round 16 (R15 de-risked):
//  - ln_elu fused into L2 GEMM epilogue, rebuilt on the VERIFIED 256-thread
//    4-wave template (R15's 512-thr/8-wave shape was the only novel construct
//    in 2x container failures). Block = 64 rows x 256 cols; wave w owns the
//    64x64 tile at col w*64 (verified fragment addressing); As[64][40] +
//    Bs[256][40] staging; LN(256) via ps/qs[64][4] cross-wave LDS reduce.
//    LDS 27.6KB, grid 782. Kills ln_elu launch + 51.2MB roundtrip; LN on
//    fp32 accs (R14-proven numerics, absmax 0.0098).
//  - everything else byte-identical to round 13 (verified, 497.1us).
// ---------------------------------------------------------------------------

#define LN_EPS 1e-5f

typedef __attribute__((ext_vector_type(8))) short bf16x8;
typedef __attribute__((ext_vector_type(4))) float f32x4;

static __device__ __forceinline__ ushort f2bf(float f) {
  union { float f; uint u; } c; c.f = f;
  uint u = c.u;
  return (ushort)((u + 0x7fffu + ((u >> 16) & 1u)) >> 16);  // RNE
}
static __device__ __forceinline__ float bf2f(ushort h) {
  union { uint u; float f; } c; c.u = (uint)h << 16;
  return c.f;
}

// ---------------- CSR build ----------------

__global__ void deg_kernel(const int* __restrict__ dst, int* __restrict__ deg, int E) {
  int e = blockIdx.x * blockDim.x + threadIdx.x;
  if (e < E) atomicAdd(&deg[dst[e]], 1);
}

__global__ void scan1_kernel(const int* __restrict__ deg, int* __restrict__ excl,
                             int* __restrict__ bsums, float* __restrict__ dinv, int N) {
  __shared__ int s[256];
  int tid = threadIdx.x;
  int i = blockIdx.x * 256 + tid;
  int v = (i < N) ? deg[i] : 0;
  s[tid] = v;
  __syncthreads();
  for (int o = 1; o < 256; o <<= 1) {
    int t = (tid >= o) ? s[tid - o] : 0;
    __syncthreads();
    if (tid >= o) s[tid] += t;
    __syncthreads();
  }
  if (i < N) {
    excl[i] = s[tid] - v;
    dinv[i] = rsqrtf((float)v + 1.0f);  // +1 self-loop
  }
  if (tid == 255) bsums[blockIdx.x] = s[tid];
}

// finalize rowptr (+ block-sum offset computed in-kernel) and seed fill cursor
__global__ void scan23_kernel(int* __restrict__ rowptr, int* __restrict__ fill,
                              const int* __restrict__ bsums, int N, int Etotal, int nb) {
  __shared__ int sh[256];
  const int tid = threadIdx.x;
  const int bix = blockIdx.x;
  int v = (tid < bix && tid < nb) ? bsums[tid] : 0;
  sh[tid] = v;
  __syncthreads();
  for (int o = 128; o > 0; o >>= 1) {
    if (tid < o) sh[tid] += sh[tid + o];
    __syncthreads();
  }
  const int off = sh[0];
  int i = bix * 256 + tid;
  if (i < N) {
    int r = rowptr[i] + off;
    rowptr[i] = r;
    fill[i] = r;
  } else if (i == N) {
    rowptr[N] = Etotal;
  }
}

__global__ void fill_kernel(const int* __restrict__ src, const int* __restrict__ dst,
                            int* __restrict__ fill, int* __restrict__ srcs, int E) {
  int e = blockIdx.x * blockDim.x + threadIdx.x;
  if (e >= E) return;
  int idx = atomicAdd(&fill[dst[e]], 1);
  srcs[idx] = src[e];
}

// ---------------- prep: weight convert + deg zero + Wl2t pad ----------------

struct WConvArgs {
  const float* w[5];
  ushort* wt[5];
  int K[5], N[5];
  int off[6];
};

__global__ void prep_kernel(WConvArgs a, int total, int* __restrict__ deg, int Nn) {
  int i = blockIdx.x * blockDim.x + threadIdx.x;
  if (i < Nn) deg[i] = 0;
  if (i < 768) a.wt[4][32000 + i] = 0;  // zero pad rows 500..511 of Wl2t
  if (i >= total) return;
  int m = 0;
  while (i >= a.off[m + 1]) m++;
  int j = i - a.off[m];
  int k = j / a.N[m], n = j - k * a.N[m];
  a.wt[m][(size_t)n * a.K[m] + k] = f2bf(a.w[m][j]);
}

// ---------------- bf16 MFMA GEMM ----------------
// C[M][N] = A[M][K] @ Bt[N][K]^T (+ bias). K % 32 == 0.
// AF32: A is fp32, converted to bf16 during LDS staging. Output bf16.
#define TBM 128
#define TBN 128
#define TBK 32
#define LDK 40

template <int AF32>
__global__ __launch_bounds__(256, 2) void mfma_gemm_kernel(
    const void* __restrict__ A, const ushort* __restrict__ Bt,
    const float* __restrict__ bias, ushort* __restrict__ Cout,
    int M, int N, int K) {
  __shared__ ushort As[TBM][LDK];
  __shared__ ushort Bs[TBN][LDK];
  const int tid = threadIdx.x;
  const int lane = tid & 63;
  const int w = tid >> 6;
  const int wm = w & 1, wn = w >> 1;
  const int quad = lane >> 4, l16 = lane & 15;
  const int rowBase = blockIdx.y * TBM;
  const int colBase = blockIdx.x * TBN;

  f32x4 acc[4][4] = {};
  const int lr = tid >> 2;
  const int lk = (tid & 3) * 8;

  for (int k0 = 0; k0 < K; k0 += TBK) {
#pragma unroll
    for (int h = 0; h < 2; h++) {
      int r = lr + h * 64;
      int grow = rowBase + r;
      if (AF32) {
        const float* Af = (const float*)A;
        float4 v0 = make_float4(0.f, 0.f, 0.f, 0.f), v1 = v0;
        if (grow < M) {
          const float* ap = Af + (size_t)grow * K + k0 + lk;
          v0 = *(const float4*)ap;
          v1 = *(const float4*)(ap + 4);
        }
        uint4 wv;
        wv.x = (uint)f2bf(v0.x) | ((uint)f2bf(v0.y) << 16);
        wv.y = (uint)f2bf(v0.z) | ((uint)f2bf(v0.w) << 16);
        wv.z = (uint)f2bf(v1.x) | ((uint)f2bf(v1.y) << 16);
        wv.w = (uint)f2bf(v1.z) | ((uint)f2bf(v1.w) << 16);
        *(uint4*)&As[r][lk] = wv;
      } else {
        const ushort* Ab = (const ushort*)A;
        uint4 va = make_uint4(0, 0, 0, 0);
        if (grow < M) va = *(const uint4*)(Ab + (size_t)grow * K + k0 + lk);
        *(uint4*)&As[r][lk] = va;
      }
      int gcol = colBase + r;
      uint4 vb = make_uint4(0, 0, 0, 0);
      if (gcol < N) vb = *(const uint4*)(Bt + (size_t)gcol * K + k0 + lk);
      *(uint4*)&Bs[r][lk] = vb;
    }
    __syncthreads();
    bf16x8 af[4], bfr[4];
#pragma unroll
    for (int i = 0; i < 4; i++) {
      af[i]  = *(const bf16x8*)&As[wm * 64 + i * 16 + l16][quad * 8];
      bfr[i] = *(const bf16x8*)&Bs[wn * 64 + i * 16 + l16][quad * 8];
    }
#pragma unroll
    for (int i = 0; i < 4; i++)
#pragma unroll
      for (int j = 0; j < 4; j++)
        acc[i][j] = __builtin_amdgcn_mfma_f32_16x16x32_bf16(af[i], bfr[j], acc[i][j], 0, 0, 0);
    __syncthreads();
  }
#pragma unroll
  for (int i = 0; i < 4; i++) {
    int row0 = rowBase + wm * 64 + i * 16 + quad * 4;
#pragma unroll
    for (int j = 0; j < 4; j++) {
      int col = colBase + wn * 64 + j * 16 + l16;
      if (col >= N) continue;
      float bv = bias ? bias[col] : 0.f;
#pragma unroll
      for (int r = 0; r < 4; r++) {
        int row = row0 + r;
        if (row >= M) continue;
        Cout[(size_t)row * N + col] = f2bf(acc[i][j][r] + bv);
      }
    }
  }
}

// ---------------- fused L2 GEMM + bias + LN(256) + ELU (256-thr template) --
// Block = 64 rows x 256 cols, K=128. 4 waves; wave w owns the 64x64 tile at
// col w*64 (verified fragment addressing). LN(256) cross-wave via
// ps/qs[64][4] (2 extra barriers). LDS 5120+20480+2048 = 27648 B.
__global__ __launch_bounds__(256) void l2gemm_ln_kernel(
    const ushort* __restrict__ A, const ushort* __restrict__ Bt,
    const float* __restrict__ bias, const float* __restrict__ gamma,
    const float* __restrict__ beta, ushort* __restrict__ Hout, int M) {
  __shared__ ushort As[64][LDK];
  __shared__ ushort Bs[256][LDK];
  __shared__ float ps[64][4];
  __shared__ float qs[64][4];
  const int tid = threadIdx.x;
  const int lane = tid & 63;
  const int w = tid >> 6;                 // 0..3 = column-tile index
  const int quad = lane >> 4, l16 = lane & 15;
  const int rowBase = blockIdx.x * 64;

  f32x4 acc[4][4] = {};
  const int lr = tid >> 2;                // 0..63
  const int lk = (tid & 3) * 8;

  for (int k0 = 0; k0 < 128; k0 += TBK) {
    {
      int grow = rowBase + lr;
      uint4 va = make_uint4(0, 0, 0, 0);
      if (grow < M) va = *(const uint4*)(A + (size_t)grow * 128 + k0 + lk);
      *(uint4*)&As[lr][lk] = va;
#pragma unroll
      for (int h = 0; h < 4; h++) {
        int r = lr + h * 64;              // 0..255, always valid (N=256)
        uint4 vb = *(const uint4*)(Bt + (size_t)r * 128 + k0 + lk);
        *(uint4*)&Bs[r][lk] = vb;
      }
    }
    __syncthreads();
    bf16x8 af[4], bfr[4];
#pragma unroll
    for (int i = 0; i < 4; i++) {
      af[i]  = *(const bf16x8*)&As[i * 16 + l16][quad * 8];
      bfr[i] = *(const bf16x8*)&Bs[w * 64 + i * 16 + l16][quad * 8];
    }
#pragma unroll
    for (int i = 0; i < 4; i++)
#pragma unroll
      for (int j = 0; j < 4; j++)
        acc[i][j] = __builtin_amdgcn_mfma_f32_16x16x32_bf16(af[i], bfr[j], acc[i][j], 0, 0, 0);
    __syncthreads();
  }

  // bias in-place
#pragma unroll
  for (int j = 0; j < 4; j++) {
    float bv = bias[w * 64 + j * 16 + l16];
#pragma unroll
    for (int i = 0; i < 4; i++)
#pragma unroll
      for (int r = 0; r < 4; r++) acc[i][j][r] += bv;
  }

  // partial row sums -> ps
#pragma unroll
  for (int i = 0; i < 4; i++) {
#pragma unroll
    for (int r = 0; r < 4; r++) {
      float p = (acc[i][0][r] + acc[i][1][r]) + (acc[i][2][r] + acc[i][3][r]);
#pragma unroll
      for (int o = 8; o >= 1; o >>= 1) p += __shfl_xor(p, o, 16);
      if (l16 == 0) ps[i * 16 + quad * 4 + r][w] = p;
    }
  }
  __syncthreads();
  float mean[4][4];
#pragma unroll
  for (int i = 0; i < 4; i++)
#pragma unroll
    for (int r = 0; r < 4; r++) {
      int lrow = i * 16 + quad * 4 + r;
      mean[i][r] = ((ps[lrow][0] + ps[lrow][1]) + (ps[lrow][2] + ps[lrow][3])) * (1.0f / 256.0f);
    }
  // partial var -> qs
#pragma unroll
  for (int i = 0; i < 4; i++) {
#pragma unroll
    for (int r = 0; r < 4; r++) {
      float q = 0.f;
#pragma unroll
      for (int j = 0; j < 4; j++) {
        float d = acc[i][j][r] - mean[i][r];
        q += d * d;
      }
#pragma unroll
      for (int o = 8; o >= 1; o >>= 1) q += __shfl_xor(q, o, 16);
      if (l16 == 0) qs[i * 16 + quad * 4 + r][w] = q;
    }
  }
  __syncthreads();
  // normalize + ELU + store
#pragma unroll
  for (int i = 0; i < 4; i++) {
#pragma unroll
    for (int r = 0; r < 4; r++) {
      int lrow = i * 16 + quad * 4 + r;
      int grow = rowBase + lrow;
      float var = ((qs[lrow][0] + qs[lrow][1]) + (qs[lrow][2] + qs[lrow][3])) * (1.0f / 256.0f);
      float rstd = rsqrtf(var + LN_EPS);
      if (grow < M) {
#pragma unroll
        for (int j = 0; j < 4; j++) {
          int col = w * 64 + j * 16 + l16;
          float y = (acc[i][j][r] - mean[i][r]) * rstd * gamma[col] + beta[col];
          y = (y > 0.f) ? y : expm1f(y);
          Hout[(size_t)grow * 256 + col] = f2bf(y);
        }
      }
    }
  }
}

// ---------------- fused L4+L5 (v2, verified R13) ----------------
__global__ __launch_bounds__(256) void l45_kernel(
    const ushort* __restrict__ A, const ushort* __restrict__ Bt1,
    const float* __restrict__ bias1, const float* __restrict__ gamma,
    const float* __restrict__ beta, const ushort* __restrict__ Bt2,
    const float* __restrict__ bias2, float* __restrict__ Cout, int M) {
  __shared__ ushort h4s[64][68];
  __shared__ __align__(16) float sout[16][500];
  const int tid = threadIdx.x;
  const int lane = tid & 63;
  const int w = tid >> 6;
  const int quad = lane >> 4, l16 = lane & 15;
  const int rowBase = blockIdx.x * 64;        // block's 64 rows
  const int waveRow = rowBase + w * 16;       // this wave's 16 rows

  // ---- phase 1: reg-B GEMM(K=128,N=64) + bias + LN + ELU -> h4s ----
  bf16x8 bfr1[4][4];
#pragma unroll
  for (int j = 0; j < 4; j++)
#pragma unroll
    for (int kk = 0; kk < 4; kk++)
      bfr1[j][kk] = *(const bf16x8*)(Bt1 + (size_t)(j * 16 + l16) * 128 + kk * 32 + quad * 8);

  const int arow = waveRow + l16;
  bf16x8 af[4] = {};
  if (arow < M) {
#pragma unroll
    for (int kk = 0; kk < 4; kk++)
      af[kk] = *(const bf16x8*)(A + (size_t)arow * 128 + kk * 32 + quad * 8);
  }

  f32x4 acc1[4] = {};
#pragma unroll
  for (int j = 0; j < 4; j++)
#pragma unroll
    for (int kk = 0; kk < 4; kk++)
      acc1[j] = __builtin_amdgcn_mfma_f32_16x16x32_bf16(af[kk], bfr1[j][kk], acc1[j], 0, 0, 0);

#pragma unroll
  for (int r = 0; r < 4; r++) {
    float v[4];
    float s = 0.f;
#pragma unroll
    for (int j = 0; j < 4; j++) {
      v[j] = acc1[j][r] + bias1[j * 16 + l16];
      s += v[j];
    }
#pragma unroll
    for (int o = 8; o >= 1; o >>= 1) s += __shfl_xor(s, o, 16);
    float mean = s * (1.0f / 64.0f);
    float q = 0.f;
#pragma unroll
    for (int j = 0; j < 4; j++) {
      float d = v[j] - mean;
      q += d * d;
    }
#pragma unroll
    for (int o = 8; o >= 1; o >>= 1) q += __shfl_xor(q, o, 16);
    float rstd = rsqrtf(q * (1.0f / 64.0f) + LN_EPS);
    int lrow = w * 16 + quad * 4 + r;  // local row 0..63
#pragma unroll
    for (int j = 0; j < 4; j++) {
      int col = j * 16 + l16;
      float y = (v[j] - mean) * rstd * gamma[col] + beta[col];
      y = (y > 0.f) ? y : expm1f(y);
      h4s[lrow][col] = f2bf(y);
    }
  }

  // preload phase-2 B fragments + bias (overlaps with other waves' phase 1)
  bf16x8 breg[8][2];
  float bvreg[8];
#pragma unroll
  for (int c = 0; c < 8; c++) {
    const int bcol = (w * 8 + c) * 16 + l16;  // 0..511
    breg[c][0] = *(const bf16x8*)(Bt2 + (size_t)bcol * 64 + quad * 8);
    breg[c][1] = *(const bf16x8*)(Bt2 + (size_t)bcol * 64 + 32 + quad * 8);
    bvreg[c] = (bcol < 500) ? bias2[bcol] : 0.f;
  }
  __syncthreads();

  // ---- phase 2: 4 slabs of 16 rows ----
#pragma unroll 1
  for (int rt = 0; rt < 4; rt++) {
    bf16x8 a0 = *(const bf16x8*)&h4s[rt * 16 + l16][quad * 8];
    bf16x8 a1 = *(const bf16x8*)&h4s[rt * 16 + l16][quad * 8 + 32];
#pragma unroll
    for (int c = 0; c < 8; c++) {
      f32x4 pacc = {0.f, 0.f, 0.f, 0.f};
      pacc = __builtin_amdgcn_mfma_f32_16x16x32_bf16(a0, breg[c][0], pacc, 0, 0, 0);
      pacc = __builtin_amdgcn_mfma_f32_16x16x32_bf16(a1, breg[c][1], pacc, 0, 0, 0);
      const int col = (w * 8 + c) * 16 + l16;
      if (col < 500) {
#pragma unroll
        for (int r = 0; r < 4; r++)
          sout[quad * 4 + r][col] = pacc[r] + bvreg[c];
      }
    }
    __syncthreads();
    // write 16 rows x 500 floats as contiguous float4 runs
#pragma unroll
    for (int k = 0; k < 8; k++) {
      int idx = k * 256 + tid;  // 0..2047; 2000 valid (16 rows * 125 float4)
      if (idx < 2000) {
        int r = idx / 125;
        int c4 = idx - r * 125;
        int grow = rowBase + rt * 16 + r;
        if (grow < M) {
          float4 v = *(float4*)&sout[r][c4 * 4];
          *(float4*)&Cout[(size_t)grow * 500 + c4 * 4] = v;
        }
      }
    }
    __syncthreads();
  }
}

// ---------------- aggregation kernels, F=128 bf16, uint4 gathers ----------------
// Max-TLP: 1 wave per node, no barriers (R14 lesson: never serialize nodes
// within a wave or put the gather behind a block barrier).

static __device__ __forceinline__ void acc8(float* a, uint4 v, float c) {
  a[0] += c * bf2f((ushort)(v.x & 0xffffu)); a[1] += c * bf2f((ushort)(v.x >> 16));
  a[2] += c * bf2f((ushort)(v.y & 0xffffu)); a[3] += c * bf2f((ushort)(v.y >> 16));
  a[4] += c * bf2f((ushort)(v.z & 0xffffu)); a[5] += c * bf2f((ushort)(v.z >> 16));
  a[6] += c * bf2f((ushort)(v.w & 0xffffu)); a[7] += c * bf2f((ushort)(v.w >> 16));
}

__global__ __launch_bounds__(256) void agg_kernel(
    const ushort* __restrict__ hb, const int* __restrict__ rowptr,
    const int* __restrict__ srcs, const float* __restrict__ dinv,
    uint* __restrict__ out, int Nn) {
  const int wave = threadIdx.x >> 6;
  const int n = blockIdx.x * 4 + wave;
  if (n >= Nn) return;
  const int lane = threadIdx.x & 63;
  const int g = lane >> 4, l16 = lane & 15;
  const uint4* h4 = (const uint4*)hb;
  const float di = dinv[n];
  float a[8] = {0.f, 0.f, 0.f, 0.f, 0.f, 0.f, 0.f, 0.f};
  if (g == 0) {
    uint4 sv = h4[(size_t)n * 16 + l16];
    acc8(a, sv, di * di);
  }
  int i = rowptr[n] + g;
  const int e = rowptr[n + 1];
  for (; i + 4 < e; i += 8) {
    int s0 = srcs[i], s1 = srcs[i + 4];
    float c0 = dinv[s0] * di, c1 = dinv[s1] * di;
    uint4 v0 = h4[(size_t)s0 * 16 + l16];
    uint4 v1 = h4[(size_t)s1 * 16 + l16];
    acc8(a, v0, c0);
    acc8(a, v1, c1);
  }
  if (i < e) {
    int s = srcs[i];
    float c = dinv[s] * di;
    uint4 v = h4[(size_t)s * 16 + l16];
    acc8(a, v, c);
  }
#pragma unroll
  for (int k = 0; k < 8; k++) {
    a[k] += __shfl_xor(a[k], 16);
    a[k] += __shfl_xor(a[k], 32);
  }
  if (g == 0) {
    uint4 o;
    o.x = (uint)f2bf(a[0]) | ((uint)f2bf(a[1]) << 16);
    o.y = (uint)f2bf(a[2]) | ((uint)f2bf(a[3]) << 16);
    o.z = (uint)f2bf(a[4]) | ((uint)f2bf(a[5]) << 16);
    o.w = (uint)f2bf(a[6]) | ((uint)f2bf(a[7]) << 16);
    ((uint4*)out)[(size_t)n * 16 + l16] = o;
  }
}

__global__ __launch_bounds__(256) void agg_ln_kernel(
    const ushort* __restrict__ hb, const int* __restrict__ rowptr,
    const int* __restrict__ srcs, const float* __restrict__ dinv,
    const float* __restrict__ bias, const float* __restrict__ gamma,
    const float* __restrict__ beta, uint* __restrict__ out, int Nn) {
  const int wave = threadIdx.x >> 6;
  const int n = blockIdx.x * 4 + wave;
  if (n >= Nn) return;
  const int lane = threadIdx.x & 63;
  const int g = lane >> 4, l16 = lane & 15;
  const uint4* h4 = (const uint4*)hb;
  const float di = dinv[n];
  float a[8] = {0.f, 0.f, 0.f, 0.f, 0.f, 0.f, 0.f, 0.f};
  if (g == 0) {
    uint4 sv = h4[(size_t)n * 16 + l16];
    acc8(a, sv, di * di);
    float4 b0 = ((const float4*)bias)[l16 * 2];
    float4 b1 = ((const float4*)bias)[l16 * 2 + 1];
    a[0] += b0.x; a[1] += b0.y; a[2] += b0.z; a[3] += b0.w;
    a[4] += b1.x; a[5] += b1.y; a[6] += b1.z; a[7] += b1.w;
  }
  int i = rowptr[n] + g;
  const int e = rowptr[n + 1];
  for (; i + 4 < e; i += 8) {
    int s0 = srcs[i], s1 = srcs[i + 4];
    float c0 = dinv[s0] * di, c1 = dinv[s1] * di;
    uint4 v0 = h4[(size_t)s0 * 16 + l16];
    uint4 v1 = h4[(size_t)s1 * 16 + l16];
    acc8(a, v0, c0);
    acc8(a, v1, c1);
  }
  if (i < e) {
    int s = srcs[i];
    float c = dinv[s] * di;
    uint4 v = h4[(size_t)s * 16 + l16];
    acc8(a, v, c);
  }
#pragma unroll
  for (int k = 0; k < 8; k++) {
    a[k] += __shfl_xor(a[k], 16);
    a[k] += __shfl_xor(a[k], 32);
  }
  float s = ((a[0] + a[1]) + (a[2] + a[3])) + ((a[4] + a[5]) + (a[6] + a[7]));
  s += __shfl_xor(s, 8);
  s += __shfl_xor(s, 4);
  s += __shfl_xor(s, 2);
  s += __shfl_xor(s, 1);
  float mean = s * (1.0f / 128.0f);
  float q = 0.f;
#pragma unroll
  for (int k = 0; k < 8; k++) {
    float d = a[k] - mean;
    q += d * d;
  }
  q += __shfl_xor(q, 8);
  q += __shfl_xor(q, 4);
  q += __shfl_xor(q, 2);
  q += __shfl_xor(q, 1);
  float rstd = rsqrtf(q * (1.0f / 128.0f) + LN_EPS);
  if (g == 0) {
    float4 g0 = ((const float4*)gamma)[l16 * 2];
    float4 g1 = ((const float4*)gamma)[l16 * 2 + 1];
    float4 e0 = ((const float4*)beta)[l16 * 2];
    float4 e1 = ((const float4*)beta)[l16 * 2 + 1];
    float gv[8] = {g0.x, g0.y, g0.z, g0.w, g1.x, g1.y, g1.z, g1.w};
    float ev[8] = {e0.x, e0.y, e0.z, e0.w, e1.x, e1.y, e1.z, e1.w};
    float y[8];
#pragma unroll
    for (int k = 0; k < 8; k++) {
      float t = (a[k] - mean) * rstd * gv[k] + ev[k];
      y[k] = (t > 0.f) ? t : expm1f(t);
    }
    uint4 o;
    o.x = (uint)f2bf(y[0]) | ((uint)f2bf(y[1]) << 16);
    o.y = (uint)f2bf(y[2]) | ((uint)f2bf(y[3]) << 16);
    o.z = (uint)f2bf(y[4]) | ((uint)f2bf(y[5]) << 16);
    o.w = (uint)f2bf(y[6]) | ((uint)f2bf(y[7]) << 16);
    ((uint4*)out)[(size_t)n * 16 + l16] = o;
  }
}

// ---------------- host ----------------

extern "C" void kernel_launch(void* const* d_in, const int* in_sizes, int n_in,
                              void* d_out, int out_size, void* d_ws, size_t ws_size,
                              hipStream_t stream) {
  const float* x   = (const float*)d_in[0];
  const int*   ei  = (const int*)d_in[1];
  const float* W1  = (const float*)d_in[2];
  const float* b1  = (const float*)d_in[3];
  const float* g1  = (const float*)d_in[4];
  const float* be1 = (const float*)d_in[5];
  const float* W2  = (const float*)d_in[6];
  const float* b2  = (const float*)d_in[7];
  const float* g2  = (const float*)d_in[8];
  const float* be2 = (const float*)d_in[9];
  const float* W3  = (const float*)d_in[10];
  const float* b3  = (const float*)d_in[11];
  const float* g3  = (const float*)d_in[12];
  const float* be3 = (const float*)d_in[13];
  const float* Wl1 = (const float*)d_in[14];
  const float* bl1 = (const float*)d_in[15];
  const float* g4  = (const float*)d_in[16];
  const float* be4 = (const float*)d_in[17];
  const float* Wl2 = (const float*)d_in[18];
  const float* bl2 = (const float*)d_in[19];

  const int N = in_sizes[0] / 128;  // 50000
  const int E = in_sizes[1] / 2;    // 800000
  const int* esrc = ei;
  const int* edst = ei + E;

  // workspace layout
  char* p = (char*)d_ws;
  ushort* Pb = (ushort*)p;            p += (size_t)N * 256 * 2;  // bf16 act buf
  ushort* Qb = (ushort*)p;            p += (size_t)N * 256 * 2;
  ushort* W1t = (ushort*)p;           p += 128 * 128 * 2;
  ushort* W2t = (ushort*)p;           p += 128 * 256 * 2;
  ushort* W3t = (ushort*)p;           p += 256 * 128 * 2;
  ushort* Wl1t = (ushort*)p;          p += 128 * 64 * 2;
  ushort* Wl2t = (ushort*)p;          p += 64 * 512 * 2;  // padded to 512 rows
  int*   srcs  = (int*)p;             p += (size_t)E * 4;
  int*   deg   = (int*)p;             p += (size_t)N * 4;
  float* dinv  = (float*)p;           p += (size_t)N * 4;
  int*   rowptr= (int*)p;             p += (size_t)(N + 2) * 4;
  int*   fill  = (int*)p;             p += (size_t)N * 4;
  int*   bsums = (int*)p;             p += 256 * 4;

  const int nb = (N + 255) / 256;
  const int eb = (E + 255) / 256;

  // ---- prep: weight convert + deg zero + Wl2t pad (one launch) ----
  WConvArgs wa;
  wa.w[0] = W1;  wa.wt[0] = W1t;  wa.K[0] = 128; wa.N[0] = 128;
  wa.w[1] = W2;  wa.wt[1] = W2t;  wa.K[1] = 128; wa.N[1] = 256;
  wa.w[2] = W3;  wa.wt[2] = W3t;  wa.K[2] = 256; wa.N[2] = 128;
  wa.w[3] = Wl1; wa.wt[3] = Wl1t; wa.K[3] = 128; wa.N[3] = 64;
  wa.w[4] = Wl2; wa.wt[4] = Wl2t; wa.K[4] = 64;  wa.N[4] = 500;
  wa.off[0] = 0;
  for (int m = 0; m < 5; m++) wa.off[m + 1] = wa.off[m] + wa.K[m] * wa.N[m];
  int wtotal = wa.off[5];
  int ptotal = wtotal > N ? wtotal : N;
  prep_kernel<<<(ptotal + 255) / 256, 256, 0, stream>>>(wa, wtotal, deg, N);

  // ---- CSR build ----
  deg_kernel<<<eb, 256, 0, stream>>>(edst, deg, E);
  scan1_kernel<<<nb, 256, 0, stream>>>(deg, rowptr, bsums, dinv, N);
  scan23_kernel<<<(N + 256) / 256, 256, 0, stream>>>(rowptr, fill, bsums, N, E, nb);
  fill_kernel<<<eb, 256, 0, stream>>>(esrc, edst, fill, srcs, E);

  const int ab = (N + 3) / 4;
  auto grid_of = [&](int M, int Nn) {
    return dim3((Nn + TBN - 1) / TBN, (M + TBM - 1) / TBM);
  };

  // L1: h1 = elu(LN(Agg(x@W1) + b1))   -- x converted fp32->bf16 in-GEMM
  mfma_gemm_kernel<1><<<grid_of(N, 128), 256, 0, stream>>>(
      x, W1t, nullptr, Pb, N, 128, 128);
  agg_ln_kernel<<<ab, 256, 0, stream>>>(Pb, rowptr, srcs, dinv, b1, g1, be1, (uint*)Qb, N);

  // L2: h2 = elu(LN(Agg(h1)@W2 + b2))  -- LN fused into GEMM epilogue
  agg_kernel<<<ab, 256, 0, stream>>>(Qb, rowptr, srcs, dinv, (uint*)Pb, N);
  l2gemm_ln_kernel<<<dim3((N + 63) / 64), 256, 0, stream>>>(
      Pb, W2t, b2, g2, be2, Qb, N);

  // L3: h3 = elu(LN(Agg(h2@W3) + b3))
  mfma_gemm_kernel<0><<<grid_of(N, 128), 256, 0, stream>>>(
      Qb, W3t, nullptr, Pb, N, 128, 256);
  agg_ln_kernel<<<ab, 256, 0, stream>>>(Pb, rowptr, srcs, dinv, b3, g3, be3, (uint*)Qb, N);

  // L4+L5 fused v2: out = elu(LN(h3@Wl1 + bl1)) @ Wl2 + bl2
  l45_kernel<<<dim3((N + 63) / 64), 256, 0, stream>>>(
      Qb, Wl1t, bl1, g4, be4, Wl2t, bl2, (float*)d_out, N);
}

// Round 14
// 463.394 us; speedup vs baseline: 1.2337x; 1.0412x over previous
//
#include <hip/hip_runtime.h>
#include <cstdint>

// ---------------------------------------------------------------------------
// GCNRecommender round 17:
//  - R16 verified (482.5us): LN-fused L2 GEMM on 256-thr template.
//  - This round: h2 is consumed ONLY by gemm3 (dense->dense). Fuse them:
//    l23_kernel = phase A (verified l2gemm_ln body, h2 -> LDS h2s[64][260])
//    + barrier + phase B (verified l45-phase-1 reg-B pattern, W3t frags in
//    64 VGPR/wave, K=256) -> h3pre. Kills 1 launch + 51.2MB h2 roundtrip.
//    LDS 60928B (<64KB, no overlay), 256 thr, no launch-bounds cap.
//  - everything else byte-identical to round 16.
// ---------------------------------------------------------------------------

#define LN_EPS 1e-5f

typedef __attribute__((ext_vector_type(8))) short bf16x8;
typedef __attribute__((ext_vector_type(4))) float f32x4;

static __device__ __forceinline__ ushort f2bf(float f) {
  union { float f; uint u; } c; c.f = f;
  uint u = c.u;
  return (ushort)((u + 0x7fffu + ((u >> 16) & 1u)) >> 16);  // RNE
}
static __device__ __forceinline__ float bf2f(ushort h) {
  union { uint u; float f; } c; c.u = (uint)h << 16;
  return c.f;
}

// ---------------- CSR build ----------------

__global__ void deg_kernel(const int* __restrict__ dst, int* __restrict__ deg, int E) {
  int e = blockIdx.x * blockDim.x + threadIdx.x;
  if (e < E) atomicAdd(&deg[dst[e]], 1);
}

__global__ void scan1_kernel(const int* __restrict__ deg, int* __restrict__ excl,
                             int* __restrict__ bsums, float* __restrict__ dinv, int N) {
  __shared__ int s[256];
  int tid = threadIdx.x;
  int i = blockIdx.x * 256 + tid;
  int v = (i < N) ? deg[i] : 0;
  s[tid] = v;
  __syncthreads();
  for (int o = 1; o < 256; o <<= 1) {
    int t = (tid >= o) ? s[tid - o] : 0;
    __syncthreads();
    if (tid >= o) s[tid] += t;
    __syncthreads();
  }
  if (i < N) {
    excl[i] = s[tid] - v;
    dinv[i] = rsqrtf((float)v + 1.0f);  // +1 self-loop
  }
  if (tid == 255) bsums[blockIdx.x] = s[tid];
}

// finalize rowptr (+ block-sum offset computed in-kernel) and seed fill cursor
__global__ void scan23_kernel(int* __restrict__ rowptr, int* __restrict__ fill,
                              const int* __restrict__ bsums, int N, int Etotal, int nb) {
  __shared__ int sh[256];
  const int tid = threadIdx.x;
  const int bix = blockIdx.x;
  int v = (tid < bix && tid < nb) ? bsums[tid] : 0;
  sh[tid] = v;
  __syncthreads();
  for (int o = 128; o > 0; o >>= 1) {
    if (tid < o) sh[tid] += sh[tid + o];
    __syncthreads();
  }
  const int off = sh[0];
  int i = bix * 256 + tid;
  if (i < N) {
    int r = rowptr[i] + off;
    rowptr[i] = r;
    fill[i] = r;
  } else if (i == N) {
    rowptr[N] = Etotal;
  }
}

__global__ void fill_kernel(const int* __restrict__ src, const int* __restrict__ dst,
                            int* __restrict__ fill, int* __restrict__ srcs, int E) {
  int e = blockIdx.x * blockDim.x + threadIdx.x;
  if (e >= E) return;
  int idx = atomicAdd(&fill[dst[e]], 1);
  srcs[idx] = src[e];
}

// ---------------- prep: weight convert + deg zero + Wl2t pad ----------------

struct WConvArgs {
  const float* w[5];
  ushort* wt[5];
  int K[5], N[5];
  int off[6];
};

__global__ void prep_kernel(WConvArgs a, int total, int* __restrict__ deg, int Nn) {
  int i = blockIdx.x * blockDim.x + threadIdx.x;
  if (i < Nn) deg[i] = 0;
  if (i < 768) a.wt[4][32000 + i] = 0;  // zero pad rows 500..511 of Wl2t
  if (i >= total) return;
  int m = 0;
  while (i >= a.off[m + 1]) m++;
  int j = i - a.off[m];
  int k = j / a.N[m], n = j - k * a.N[m];
  a.wt[m][(size_t)n * a.K[m] + k] = f2bf(a.w[m][j]);
}

// ---------------- bf16 MFMA GEMM ----------------
// C[M][N] = A[M][K] @ Bt[N][K]^T (+ bias). K % 32 == 0.
// AF32: A is fp32, converted to bf16 during LDS staging. Output bf16.
#define TBM 128
#define TBN 128
#define TBK 32
#define LDK 40

template <int AF32>
__global__ __launch_bounds__(256, 2) void mfma_gemm_kernel(
    const void* __restrict__ A, const ushort* __restrict__ Bt,
    const float* __restrict__ bias, ushort* __restrict__ Cout,
    int M, int N, int K) {
  __shared__ ushort As[TBM][LDK];
  __shared__ ushort Bs[TBN][LDK];
  const int tid = threadIdx.x;
  const int lane = tid & 63;
  const int w = tid >> 6;
  const int wm = w & 1, wn = w >> 1;
  const int quad = lane >> 4, l16 = lane & 15;
  const int rowBase = blockIdx.y * TBM;
  const int colBase = blockIdx.x * TBN;

  f32x4 acc[4][4] = {};
  const int lr = tid >> 2;
  const int lk = (tid & 3) * 8;

  for (int k0 = 0; k0 < K; k0 += TBK) {
#pragma unroll
    for (int h = 0; h < 2; h++) {
      int r = lr + h * 64;
      int grow = rowBase + r;
      if (AF32) {
        const float* Af = (const float*)A;
        float4 v0 = make_float4(0.f, 0.f, 0.f, 0.f), v1 = v0;
        if (grow < M) {
          const float* ap = Af + (size_t)grow * K + k0 + lk;
          v0 = *(const float4*)ap;
          v1 = *(const float4*)(ap + 4);
        }
        uint4 wv;
        wv.x = (uint)f2bf(v0.x) | ((uint)f2bf(v0.y) << 16);
        wv.y = (uint)f2bf(v0.z) | ((uint)f2bf(v0.w) << 16);
        wv.z = (uint)f2bf(v1.x) | ((uint)f2bf(v1.y) << 16);
        wv.w = (uint)f2bf(v1.z) | ((uint)f2bf(v1.w) << 16);
        *(uint4*)&As[r][lk] = wv;
      } else {
        const ushort* Ab = (const ushort*)A;
        uint4 va = make_uint4(0, 0, 0, 0);
        if (grow < M) va = *(const uint4*)(Ab + (size_t)grow * K + k0 + lk);
        *(uint4*)&As[r][lk] = va;
      }
      int gcol = colBase + r;
      uint4 vb = make_uint4(0, 0, 0, 0);
      if (gcol < N) vb = *(const uint4*)(Bt + (size_t)gcol * K + k0 + lk);
      *(uint4*)&Bs[r][lk] = vb;
    }
    __syncthreads();
    bf16x8 af[4], bfr[4];
#pragma unroll
    for (int i = 0; i < 4; i++) {
      af[i]  = *(const bf16x8*)&As[wm * 64 + i * 16 + l16][quad * 8];
      bfr[i] = *(const bf16x8*)&Bs[wn * 64 + i * 16 + l16][quad * 8];
    }
#pragma unroll
    for (int i = 0; i < 4; i++)
#pragma unroll
      for (int j = 0; j < 4; j++)
        acc[i][j] = __builtin_amdgcn_mfma_f32_16x16x32_bf16(af[i], bfr[j], acc[i][j], 0, 0, 0);
    __syncthreads();
  }
#pragma unroll
  for (int i = 0; i < 4; i++) {
    int row0 = rowBase + wm * 64 + i * 16 + quad * 4;
#pragma unroll
    for (int j = 0; j < 4; j++) {
      int col = colBase + wn * 64 + j * 16 + l16;
      if (col >= N) continue;
      float bv = bias ? bias[col] : 0.f;
#pragma unroll
      for (int r = 0; r < 4; r++) {
        int row = row0 + r;
        if (row >= M) continue;
        Cout[(size_t)row * N + col] = f2bf(acc[i][j][r] + bv);
      }
    }
  }
}

// ---------------- fused L2+L3-GEMM ----------------
// Phase A (verified l2gemm_ln body): h2_tile(64x256) = elu(LN256(aggh1_tile
//   @ W2t + b2)) -> LDS h2s (bf16, unconditional; OOB rows are finite).
// Phase B (verified l45-phase-1 reg-B pattern): h3pre_tile(64x128) =
//   h2s @ W3t (K=256, wave owns 32 cols, 16 B-frags = 64 VGPR) -> Hout.
// LDS: 5120 + 20480 + 1024 + 1024 + 33280 = 60928 B; 2 blocks/CU.
__global__ __launch_bounds__(256) void l23_kernel(
    const ushort* __restrict__ A, const ushort* __restrict__ Bt2,
    const float* __restrict__ bias2, const float* __restrict__ gamma2,
    const float* __restrict__ beta2, const ushort* __restrict__ Bt3,
    ushort* __restrict__ Hout, int M) {
  __shared__ ushort As[64][LDK];
  __shared__ ushort Bs[256][LDK];
  __shared__ float ps[64][4];
  __shared__ float qs[64][4];
  __shared__ ushort h2s[64][260];
  const int tid = threadIdx.x;
  const int lane = tid & 63;
  const int w = tid >> 6;                 // 0..3
  const int quad = lane >> 4, l16 = lane & 15;
  const int rowBase = blockIdx.x * 64;

  // ---- phase A: GEMM(K=128,N=256) + bias + LN(256) + ELU -> h2s ----
  f32x4 acc[4][4] = {};
  const int lr = tid >> 2;                // 0..63
  const int lk = (tid & 3) * 8;

  for (int k0 = 0; k0 < 128; k0 += TBK) {
    {
      int grow = rowBase + lr;
      uint4 va = make_uint4(0, 0, 0, 0);
      if (grow < M) va = *(const uint4*)(A + (size_t)grow * 128 + k0 + lk);
      *(uint4*)&As[lr][lk] = va;
#pragma unroll
      for (int h = 0; h < 4; h++) {
        int r = lr + h * 64;              // 0..255, always valid (N=256)
        uint4 vb = *(const uint4*)(Bt2 + (size_t)r * 128 + k0 + lk);
        *(uint4*)&Bs[r][lk] = vb;
      }
    }
    __syncthreads();
    bf16x8 af[4], bfr[4];
#pragma unroll
    for (int i = 0; i < 4; i++) {
      af[i]  = *(const bf16x8*)&As[i * 16 + l16][quad * 8];
      bfr[i] = *(const bf16x8*)&Bs[w * 64 + i * 16 + l16][quad * 8];
    }
#pragma unroll
    for (int i = 0; i < 4; i++)
#pragma unroll
      for (int j = 0; j < 4; j++)
        acc[i][j] = __builtin_amdgcn_mfma_f32_16x16x32_bf16(af[i], bfr[j], acc[i][j], 0, 0, 0);
    __syncthreads();
  }

  // bias in-place
#pragma unroll
  for (int j = 0; j < 4; j++) {
    float bv = bias2[w * 64 + j * 16 + l16];
#pragma unroll
    for (int i = 0; i < 4; i++)
#pragma unroll
      for (int r = 0; r < 4; r++) acc[i][j][r] += bv;
  }

  // partial row sums -> ps
#pragma unroll
  for (int i = 0; i < 4; i++) {
#pragma unroll
    for (int r = 0; r < 4; r++) {
      float p = (acc[i][0][r] + acc[i][1][r]) + (acc[i][2][r] + acc[i][3][r]);
#pragma unroll
      for (int o = 8; o >= 1; o >>= 1) p += __shfl_xor(p, o, 16);
      if (l16 == 0) ps[i * 16 + quad * 4 + r][w] = p;
    }
  }
  __syncthreads();
  float mean[4][4];
#pragma unroll
  for (int i = 0; i < 4; i++)
#pragma unroll
    for (int r = 0; r < 4; r++) {
      int lrow = i * 16 + quad * 4 + r;
      mean[i][r] = ((ps[lrow][0] + ps[lrow][1]) + (ps[lrow][2] + ps[lrow][3])) * (1.0f / 256.0f);
    }
  // partial var -> qs
#pragma unroll
  for (int i = 0; i < 4; i++) {
#pragma unroll
    for (int r = 0; r < 4; r++) {
      float q = 0.f;
#pragma unroll
      for (int j = 0; j < 4; j++) {
        float d = acc[i][j][r] - mean[i][r];
        q += d * d;
      }
#pragma unroll
      for (int o = 8; o >= 1; o >>= 1) q += __shfl_xor(q, o, 16);
      if (l16 == 0) qs[i * 16 + quad * 4 + r][w] = q;
    }
  }
  __syncthreads();
  // normalize + ELU -> h2s (unconditional; OOB rows finite: zeros -> rsqrt(eps))
#pragma unroll
  for (int i = 0; i < 4; i++) {
#pragma unroll
    for (int r = 0; r < 4; r++) {
      int lrow = i * 16 + quad * 4 + r;
      float var = ((qs[lrow][0] + qs[lrow][1]) + (qs[lrow][2] + qs[lrow][3])) * (1.0f / 256.0f);
      float rstd = rsqrtf(var + LN_EPS);
#pragma unroll
      for (int j = 0; j < 4; j++) {
        int col = w * 64 + j * 16 + l16;
        float y = (acc[i][j][r] - mean[i][r]) * rstd * gamma2[col] + beta2[col];
        y = (y > 0.f) ? y : expm1f(y);
        h2s[lrow][col] = f2bf(y);
      }
    }
  }
  __syncthreads();

  // ---- phase B: h3pre(64x128) = h2s(64x256) @ W3t(128x256)^T ----
  // wave w owns cols w*32..w*32+31 (2 col-tiles); 8 k-slices.
  bf16x8 bfr3[2][8];
#pragma unroll
  for (int j = 0; j < 2; j++)
#pragma unroll
    for (int kk = 0; kk < 8; kk++)
      bfr3[j][kk] = *(const bf16x8*)(Bt3 + (size_t)(w * 32 + j * 16 + l16) * 256 + kk * 32 + quad * 8);

  f32x4 acc3[4][2] = {};
#pragma unroll
  for (int i = 0; i < 4; i++) {
#pragma unroll
    for (int kk = 0; kk < 8; kk++) {
      bf16x8 af = *(const bf16x8*)&h2s[i * 16 + l16][kk * 32 + quad * 8];
#pragma unroll
      for (int j = 0; j < 2; j++)
        acc3[i][j] = __builtin_amdgcn_mfma_f32_16x16x32_bf16(af, bfr3[j][kk], acc3[i][j], 0, 0, 0);
    }
  }
#pragma unroll
  for (int i = 0; i < 4; i++) {
#pragma unroll
    for (int j = 0; j < 2; j++) {
      int col = w * 32 + j * 16 + l16;
#pragma unroll
      for (int r = 0; r < 4; r++) {
        int row = rowBase + i * 16 + quad * 4 + r;
        if (row < M) Hout[(size_t)row * 128 + col] = f2bf(acc3[i][j][r]);
      }
    }
  }
}

// ---------------- fused L4+L5 (v2, verified R13) ----------------
__global__ __launch_bounds__(256) void l45_kernel(
    const ushort* __restrict__ A, const ushort* __restrict__ Bt1,
    const float* __restrict__ bias1, const float* __restrict__ gamma,
    const float* __restrict__ beta, const ushort* __restrict__ Bt2,
    const float* __restrict__ bias2, float* __restrict__ Cout, int M) {
  __shared__ ushort h4s[64][68];
  __shared__ __align__(16) float sout[16][500];
  const int tid = threadIdx.x;
  const int lane = tid & 63;
  const int w = tid >> 6;
  const int quad = lane >> 4, l16 = lane & 15;
  const int rowBase = blockIdx.x * 64;        // block's 64 rows
  const int waveRow = rowBase + w * 16;       // this wave's 16 rows

  // ---- phase 1: reg-B GEMM(K=128,N=64) + bias + LN + ELU -> h4s ----
  bf16x8 bfr1[4][4];
#pragma unroll
  for (int j = 0; j < 4; j++)
#pragma unroll
    for (int kk = 0; kk < 4; kk++)
      bfr1[j][kk] = *(const bf16x8*)(Bt1 + (size_t)(j * 16 + l16) * 128 + kk * 32 + quad * 8);

  const int arow = waveRow + l16;
  bf16x8 af[4] = {};
  if (arow < M) {
#pragma unroll
    for (int kk = 0; kk < 4; kk++)
      af[kk] = *(const bf16x8*)(A + (size_t)arow * 128 + kk * 32 + quad * 8);
  }

  f32x4 acc1[4] = {};
#pragma unroll
  for (int j = 0; j < 4; j++)
#pragma unroll
    for (int kk = 0; kk < 4; kk++)
      acc1[j] = __builtin_amdgcn_mfma_f32_16x16x32_bf16(af[kk], bfr1[j][kk], acc1[j], 0, 0, 0);

#pragma unroll
  for (int r = 0; r < 4; r++) {
    float v[4];
    float s = 0.f;
#pragma unroll
    for (int j = 0; j < 4; j++) {
      v[j] = acc1[j][r] + bias1[j * 16 + l16];
      s += v[j];
    }
#pragma unroll
    for (int o = 8; o >= 1; o >>= 1) s += __shfl_xor(s, o, 16);
    float mean = s * (1.0f / 64.0f);
    float q = 0.f;
#pragma unroll
    for (int j = 0; j < 4; j++) {
      float d = v[j] - mean;
      q += d * d;
    }
#pragma unroll
    for (int o = 8; o >= 1; o >>= 1) q += __shfl_xor(q, o, 16);
    float rstd = rsqrtf(q * (1.0f / 64.0f) + LN_EPS);
    int lrow = w * 16 + quad * 4 + r;  // local row 0..63
#pragma unroll
    for (int j = 0; j < 4; j++) {
      int col = j * 16 + l16;
      float y = (v[j] - mean) * rstd * gamma[col] + beta[col];
      y = (y > 0.f) ? y : expm1f(y);
      h4s[lrow][col] = f2bf(y);
    }
  }

  // preload phase-2 B fragments + bias (overlaps with other waves' phase 1)
  bf16x8 breg[8][2];
  float bvreg[8];
#pragma unroll
  for (int c = 0; c < 8; c++) {
    const int bcol = (w * 8 + c) * 16 + l16;  // 0..511
    breg[c][0] = *(const bf16x8*)(Bt2 + (size_t)bcol * 64 + quad * 8);
    breg[c][1] = *(const bf16x8*)(Bt2 + (size_t)bcol * 64 + 32 + quad * 8);
    bvreg[c] = (bcol < 500) ? bias2[bcol] : 0.f;
  }
  __syncthreads();

  // ---- phase 2: 4 slabs of 16 rows ----
#pragma unroll 1
  for (int rt = 0; rt < 4; rt++) {
    bf16x8 a0 = *(const bf16x8*)&h4s[rt * 16 + l16][quad * 8];
    bf16x8 a1 = *(const bf16x8*)&h4s[rt * 16 + l16][quad * 8 + 32];
#pragma unroll
    for (int c = 0; c < 8; c++) {
      f32x4 pacc = {0.f, 0.f, 0.f, 0.f};
      pacc = __builtin_amdgcn_mfma_f32_16x16x32_bf16(a0, breg[c][0], pacc, 0, 0, 0);
      pacc = __builtin_amdgcn_mfma_f32_16x16x32_bf16(a1, breg[c][1], pacc, 0, 0, 0);
      const int col = (w * 8 + c) * 16 + l16;
      if (col < 500) {
#pragma unroll
        for (int r = 0; r < 4; r++)
          sout[quad * 4 + r][col] = pacc[r] + bvreg[c];
      }
    }
    __syncthreads();
    // write 16 rows x 500 floats as contiguous float4 runs
#pragma unroll
    for (int k = 0; k < 8; k++) {
      int idx = k * 256 + tid;  // 0..2047; 2000 valid (16 rows * 125 float4)
      if (idx < 2000) {
        int r = idx / 125;
        int c4 = idx - r * 125;
        int grow = rowBase + rt * 16 + r;
        if (grow < M) {
          float4 v = *(float4*)&sout[r][c4 * 4];
          *(float4*)&Cout[(size_t)grow * 500 + c4 * 4] = v;
        }
      }
    }
    __syncthreads();
  }
}

// ---------------- aggregation kernels, F=128 bf16, uint4 gathers ----------------
// Max-TLP: 1 wave per node, no barriers (R14 lesson: never serialize nodes
// within a wave or put the gather behind a block barrier).

static __device__ __forceinline__ void acc8(float* a, uint4 v, float c) {
  a[0] += c * bf2f((ushort)(v.x & 0xffffu)); a[1] += c * bf2f((ushort)(v.x >> 16));
  a[2] += c * bf2f((ushort)(v.y & 0xffffu)); a[3] += c * bf2f((ushort)(v.y >> 16));
  a[4] += c * bf2f((ushort)(v.z & 0xffffu)); a[5] += c * bf2f((ushort)(v.z >> 16));
  a[6] += c * bf2f((ushort)(v.w & 0xffffu)); a[7] += c * bf2f((ushort)(v.w >> 16));
}

__global__ __launch_bounds__(256) void agg_kernel(
    const ushort* __restrict__ hb, const int* __restrict__ rowptr,
    const int* __restrict__ srcs, const float* __restrict__ dinv,
    uint* __restrict__ out, int Nn) {
  const int wave = threadIdx.x >> 6;
  const int n = blockIdx.x * 4 + wave;
  if (n >= Nn) return;
  const int lane = threadIdx.x & 63;
  const int g = lane >> 4, l16 = lane & 15;
  const uint4* h4 = (const uint4*)hb;
  const float di = dinv[n];
  float a[8] = {0.f, 0.f, 0.f, 0.f, 0.f, 0.f, 0.f, 0.f};
  if (g == 0) {
    uint4 sv = h4[(size_t)n * 16 + l16];
    acc8(a, sv, di * di);
  }
  int i = rowptr[n] + g;
  const int e = rowptr[n + 1];
  for (; i + 4 < e; i += 8) {
    int s0 = srcs[i], s1 = srcs[i + 4];
    float c0 = dinv[s0] * di, c1 = dinv[s1] * di;
    uint4 v0 = h4[(size_t)s0 * 16 + l16];
    uint4 v1 = h4[(size_t)s1 * 16 + l16];
    acc8(a, v0, c0);
    acc8(a, v1, c1);
  }
  if (i < e) {
    int s = srcs[i];
    float c = dinv[s] * di;
    uint4 v = h4[(size_t)s * 16 + l16];
    acc8(a, v, c);
  }
#pragma unroll
  for (int k = 0; k < 8; k++) {
    a[k] += __shfl_xor(a[k], 16);
    a[k] += __shfl_xor(a[k], 32);
  }
  if (g == 0) {
    uint4 o;
    o.x = (uint)f2bf(a[0]) | ((uint)f2bf(a[1]) << 16);
    o.y = (uint)f2bf(a[2]) | ((uint)f2bf(a[3]) << 16);
    o.z = (uint)f2bf(a[4]) | ((uint)f2bf(a[5]) << 16);
    o.w = (uint)f2bf(a[6]) | ((uint)f2bf(a[7]) << 16);
    ((uint4*)out)[(size_t)n * 16 + l16] = o;
  }
}

__global__ __launch_bounds__(256) void agg_ln_kernel(
    const ushort* __restrict__ hb, const int* __restrict__ rowptr,
    const int* __restrict__ srcs, const float* __restrict__ dinv,
    const float* __restrict__ bias, const float* __restrict__ gamma,
    const float* __restrict__ beta, uint* __restrict__ out, int Nn) {
  const int wave = threadIdx.x >> 6;
  const int n = blockIdx.x * 4 + wave;
  if (n >= Nn) return;
  const int lane = threadIdx.x & 63;
  const int g = lane >> 4, l16 = lane & 15;
  const uint4* h4 = (const uint4*)hb;
  const float di = dinv[n];
  float a[8] = {0.f, 0.f, 0.f, 0.f, 0.f, 0.f, 0.f, 0.f};
  if (g == 0) {
    uint4 sv = h4[(size_t)n * 16 + l16];
    acc8(a, sv, di * di);
    float4 b0 = ((const float4*)bias)[l16 * 2];
    float4 b1 = ((const float4*)bias)[l16 * 2 + 1];
    a[0] += b0.x; a[1] += b0.y; a[2] += b0.z; a[3] += b0.w;
    a[4] += b1.x; a[5] += b1.y; a[6] += b1.z; a[7] += b1.w;
  }
  int i = rowptr[n] + g;
  const int e = rowptr[n + 1];
  for (; i + 4 < e; i += 8) {
    int s0 = srcs[i], s1 = srcs[i + 4];
    float c0 = dinv[s0] * di, c1 = dinv[s1] * di;
    uint4 v0 = h4[(size_t)s0 * 16 + l16];
    uint4 v1 = h4[(size_t)s1 * 16 + l16];
    acc8(a, v0, c0);
    acc8(a, v1, c1);
  }
  if (i < e) {
    int s = srcs[i];
    float c = dinv[s] * di;
    uint4 v = h4[(size_t)s * 16 + l16];
    acc8(a, v, c);
  }
#pragma unroll
  for (int k = 0; k < 8; k++) {
    a[k] += __shfl_xor(a[k], 16);
    a[k] += __shfl_xor(a[k], 32);
  }
  float s = ((a[0] + a[1]) + (a[2] + a[3])) + ((a[4] + a[5]) + (a[6] + a[7]));
  s += __shfl_xor(s, 8);
  s += __shfl_xor(s, 4);
  s += __shfl_xor(s, 2);
  s += __shfl_xor(s, 1);
  float mean = s * (1.0f / 128.0f);
  float q = 0.f;
#pragma unroll
  for (int k = 0; k < 8; k++) {
    float d = a[k] - mean;
    q += d * d;
  }
  q += __shfl_xor(q, 8);
  q += __shfl_xor(q, 4);
  q += __shfl_xor(q, 2);
  q += __shfl_xor(q, 1);
  float rstd = rsqrtf(q * (1.0f / 128.0f) + LN_EPS);
  if (g == 0) {
    float4 g0 = ((const float4*)gamma)[l16 * 2];
    float4 g1 = ((const float4*)gamma)[l16 * 2 + 1];
    float4 e0 = ((const float4*)beta)[l16 * 2];
    float4 e1 = ((const float4*)beta)[l16 * 2 + 1];
    float gv[8] = {g0.x, g0.y, g0.z, g0.w, g1.x, g1.y, g1.z, g1.w};
    float ev[8] = {e0.x, e0.y, e0.z, e0.w, e1.x, e1.y, e1.z, e1.w};
    float y[8];
#pragma unroll
    for (int k = 0; k < 8; k++) {
      float t = (a[k] - mean) * rstd * gv[k] + ev[k];
      y[k] = (t > 0.f) ? t : expm1f(t);
    }
    uint4 o;
    o.x = (uint)f2bf(y[0]) | ((uint)f2bf(y[1]) << 16);
    o.y = (uint)f2bf(y[2]) | ((uint)f2bf(y[3]) << 16);
    o.z = (uint)f2bf(y[4]) | ((uint)f2bf(y[5]) << 16);
    o.w = (uint)f2bf(y[6]) | ((uint)f2bf(y[7]) << 16);
    ((uint4*)out)[(size_t)n * 16 + l16] = o;
  }
}

// ---------------- host ----------------

extern "C" void kernel_launch(void* const* d_in, const int* in_sizes, int n_in,
                              void* d_out, int out_size, void* d_ws, size_t ws_size,
                              hipStream_t stream) {
  const float* x   = (const float*)d_in[0];
  const int*   ei  = (const int*)d_in[1];
  const float* W1  = (const float*)d_in[2];
  const float* b1  = (const float*)d_in[3];
  const float* g1  = (const float*)d_in[4];
  const float* be1 = (const float*)d_in[5];
  const float* W2  = (const float*)d_in[6];
  const float* b2  = (const float*)d_in[7];
  const float* g2  = (const float*)d_in[8];
  const float* be2 = (const float*)d_in[9];
  const float* W3  = (const float*)d_in[10];
  const float* b3  = (const float*)d_in[11];
  const float* g3  = (const float*)d_in[12];
  const float* be3 = (const float*)d_in[13];
  const float* Wl1 = (const float*)d_in[14];
  const float* bl1 = (const float*)d_in[15];
  const float* g4  = (const float*)d_in[16];
  const float* be4 = (const float*)d_in[17];
  const float* Wl2 = (const float*)d_in[18];
  const float* bl2 = (const float*)d_in[19];

  const int N = in_sizes[0] / 128;  // 50000
  const int E = in_sizes[1] / 2;    // 800000
  const int* esrc = ei;
  const int* edst = ei + E;

  // workspace layout
  char* p = (char*)d_ws;
  ushort* Pb = (ushort*)p;            p += (size_t)N * 256 * 2;  // bf16 act buf
  ushort* Qb = (ushort*)p;            p += (size_t)N * 256 * 2;
  ushort* W1t = (ushort*)p;           p += 128 * 128 * 2;
  ushort* W2t = (ushort*)p;           p += 128 * 256 * 2;
  ushort* W3t = (ushort*)p;           p += 256 * 128 * 2;
  ushort* Wl1t = (ushort*)p;          p += 128 * 64 * 2;
  ushort* Wl2t = (ushort*)p;          p += 64 * 512 * 2;  // padded to 512 rows
  int*   srcs  = (int*)p;             p += (size_t)E * 4;
  int*   deg   = (int*)p;             p += (size_t)N * 4;
  float* dinv  = (float*)p;           p += (size_t)N * 4;
  int*   rowptr= (int*)p;             p += (size_t)(N + 2) * 4;
  int*   fill  = (int*)p;             p += (size_t)N * 4;
  int*   bsums = (int*)p;             p += 256 * 4;

  const int nb = (N + 255) / 256;
  const int eb = (E + 255) / 256;

  // ---- prep: weight convert + deg zero + Wl2t pad (one launch) ----
  WConvArgs wa;
  wa.w[0] = W1;  wa.wt[0] = W1t;  wa.K[0] = 128; wa.N[0] = 128;
  wa.w[1] = W2;  wa.wt[1] = W2t;  wa.K[1] = 128; wa.N[1] = 256;
  wa.w[2] = W3;  wa.wt[2] = W3t;  wa.K[2] = 256; wa.N[2] = 128;
  wa.w[3] = Wl1; wa.wt[3] = Wl1t; wa.K[3] = 128; wa.N[3] = 64;
  wa.w[4] = Wl2; wa.wt[4] = Wl2t; wa.K[4] = 64;  wa.N[4] = 500;
  wa.off[0] = 0;
  for (int m = 0; m < 5; m++) wa.off[m + 1] = wa.off[m] + wa.K[m] * wa.N[m];
  int wtotal = wa.off[5];
  int ptotal = wtotal > N ? wtotal : N;
  prep_kernel<<<(ptotal + 255) / 256, 256, 0, stream>>>(wa, wtotal, deg, N);

  // ---- CSR build ----
  deg_kernel<<<eb, 256, 0, stream>>>(edst, deg, E);
  scan1_kernel<<<nb, 256, 0, stream>>>(deg, rowptr, bsums, dinv, N);
  scan23_kernel<<<(N + 256) / 256, 256, 0, stream>>>(rowptr, fill, bsums, N, E, nb);
  fill_kernel<<<eb, 256, 0, stream>>>(esrc, edst, fill, srcs, E);

  const int ab = (N + 3) / 4;
  auto grid_of = [&](int M, int Nn) {
    return dim3((Nn + TBN - 1) / TBN, (M + TBM - 1) / TBM);
  };

  // L1: h1 = elu(LN(Agg(x@W1) + b1))   -- x converted fp32->bf16 in-GEMM
  mfma_gemm_kernel<1><<<grid_of(N, 128), 256, 0, stream>>>(
      x, W1t, nullptr, Pb, N, 128, 128);
  agg_ln_kernel<<<ab, 256, 0, stream>>>(Pb, rowptr, srcs, dinv, b1, g1, be1, (uint*)Qb, N);

  // L2+L3-GEMM fused: h3pre = elu(LN(Agg(h1)@W2 + b2)) @ W3
  agg_kernel<<<ab, 256, 0, stream>>>(Qb, rowptr, srcs, dinv, (uint*)Pb, N);
  l23_kernel<<<dim3((N + 63) / 64), 256, 0, stream>>>(
      Pb, W2t, b2, g2, be2, W3t, Qb, N);

  // L3 agg: h3 = elu(LN(Agg(h3pre) + b3))
  agg_ln_kernel<<<ab, 256, 0, stream>>>(Qb, rowptr, srcs, dinv, b3, g3, be3, (uint*)Pb, N);

  // L4+L5 fused v2: out = elu(LN(h3@Wl1 + bl1)) @ Wl2 + bl2
  l45_kernel<<<dim3((N + 63) / 64), 256, 0, stream>>>(
      Pb, Wl1t, bl1, g4, be4, Wl2t, bl2, (float*)d_out, N);
}